// Round 14
// baseline (222.282 us; speedup 1.0000x reference)
//
#include <hip/hip_runtime.h>
#include <hip/hip_bf16.h>
#include <stdint.h>

#define BATCH 16384
#define D 1024
#define NCLS 1000
#define NPROTO 5000
#define NPROTO_PAD 5120
#define NGRP 320            // proto col-groups of 16
#define NRGRP 1024          // batch row-groups of 16
#define BM 128              // rows per block
#define COLHALF 2560
#define NCH 5               // chunks of 512 cols per half
#define NKT 32
#define KT_B (NGRP * 512)   // pbf elems per kt
#define KT_A (NRGRP * 512)  // abf elems per kt

typedef float f32x4 __attribute__((ext_vector_type(4)));
typedef __bf16 bf16x8 __attribute__((ext_vector_type(8)));

__device__ __forceinline__ unsigned short f2bf(float x) {
    unsigned u = __float_as_uint(x);
    u += 0x7FFFu + ((u >> 16) & 1u);   // RNE
    return (unsigned short)(u >> 16);
}

// ---------- normalize rows of z and P to bf16, MFMA-fragment-packed ----------
// abf[kt][rgrp][lane][8]: row = rgrp*16 + (lane&15), k = kt*32 + (lane>>4)*8 + e
// pbf[kt][grp][lane][8]:  col = grp*16 + (lane&15), same k mapping
__global__ __launch_bounds__(256) void k_prep(
        const float* __restrict__ z, const float* __restrict__ P,
        unsigned short* __restrict__ abf, unsigned short* __restrict__ pbf) {
    const int b = blockIdx.x;
    const int t = threadIdx.x;
    const int e0 = 4 * t;
    const int kt = e0 >> 5;
    const int lk = (e0 >> 3) & 3;
    const int e = e0 & 7;
    const float* src = nullptr;
    unsigned short* dst;
    if (b < BATCH) {
        src = z + (size_t)b * D;
        dst = abf + (((size_t)kt * NRGRP + (b >> 4)) * 64 + (b & 15) + 16 * lk) * 8 + e;
    } else {
        const int r = b - BATCH;
        dst = pbf + (((size_t)kt * NGRP + (r >> 4)) * 64 + (r & 15) + 16 * lk) * 8 + e;
        if (r < NPROTO) src = P + (size_t)r * D;
    }
    if (src == nullptr) {                 // padded proto row -> zeros
        *(ushort4*)dst = make_ushort4(0, 0, 0, 0);
        return;
    }
    float4 v = ((const float4*)src)[t];
    float ss = v.x * v.x + v.y * v.y + v.z * v.z + v.w * v.w;
    #pragma unroll
    for (int o = 32; o >= 1; o >>= 1) ss += __shfl_xor(ss, o);
    __shared__ float red[4];
    const int wave = t >> 6;
    if ((t & 63) == 0) red[wave] = ss;
    __syncthreads();
    const float s = red[0] + red[1] + red[2] + red[3];
    const float inv = 1.0f / fmaxf(sqrtf(s), 1e-12f);
    ushort4 o4;
    o4.x = f2bf(v.x * inv); o4.y = f2bf(v.y * inv);
    o4.z = f2bf(v.z * inv); o4.w = f2bf(v.w * inv);
    *(ushort4*)dst = o4;
}

// async global->LDS, 16B per lane, dest = wave-uniform base + lane*16
#define GLL(gp, lp) __builtin_amdgcn_global_load_lds( \
    (__attribute__((address_space(1))) const unsigned int*)(const void*)(gp), \
    (__attribute__((address_space(3))) unsigned int*)(void*)(lp), 16, 0, 0)

#define MM(A, B, C) __builtin_amdgcn_mfma_f32_16x16x32_bf16(A, B, C, 0, 0, 0)

// ---------- BM=128 GEMM: A windowed through LDS ring, B streamed to regs ----
// 256 blocks (128 row-tiles x 2 col-halves) x 1024 threads (16 waves, 4/SIMD).
// Wave tile 64x64: waves (w>>3)=row-half, (w&7)=col-slot. Per 8-kt window:
// stage 64KB of A (4 GLL/thread) into ring half, one vmcnt(0)+barrier.
__global__ __launch_bounds__(1024, 4) void k_gemm(
        const unsigned short* __restrict__ abf,
        const unsigned short* __restrict__ pbf,
        const int* __restrict__ y,
        float* __restrict__ outP, float* __restrict__ outN) {
    // LA[buf][slab 0..7][rgrp 0..7][lane][8]  = 2 x 64 KiB
    __shared__ __align__(16) unsigned short LA[2][8][8][64][8];
    __shared__ float redP[16][64];
    __shared__ float redN[16][64];

    const int t = threadIdx.x;
    const int w = t >> 6, lane = t & 63;
    const int lm = lane & 15, lk = lane >> 4;
    const int wh = w >> 3;               // row-half 0/1
    const int wc = w & 7;                // col-slot 0..7
    const int bid = blockIdx.x;
    const int rowbase = (bid >> 1) * BM;
    const int ch = bid & 1;              // col-half
    const int rb16 = rowbase >> 4;

    redP[w][lane] = -INFINITY;
    redN[w][lane] = -INFINITY;

    // stage source base: wave w supplies rgrp wc of each of its 4 slabs
    const unsigned short* aw = abf + ((size_t)(rb16 + wc)) * 512 + lane * 8;

#define STAGE(BUF, WIN) do {                                                 \
    _Pragma("unroll")                                                        \
    for (int j_ = 0; j_ < 4; ++j_) {                                         \
        const int s_ = 2 * j_ + wh;                                          \
        GLL(aw + (size_t)((WIN) * 8 + s_) * KT_A, &LA[BUF][s_][wc][0][0]);   \
    }                                                                        \
} while (0)

    // prologue: stage window 0 into buf 0
    STAGE(0, 0);
    asm volatile("s_waitcnt vmcnt(0)" ::: "memory");
    __syncthreads();

    int buf = 0;
    #pragma unroll 1
    for (int c = 0; c < NCH; ++c) {
        const unsigned short* pBc =
            pbf + (size_t)(ch * 160 + c * 32 + wc * 4) * 512 + lane * 8;

        f32x4 acc[4][4];
        #pragma unroll
        for (int mi = 0; mi < 4; ++mi)
            #pragma unroll
            for (int ni = 0; ni < 4; ++ni) {
                f32x4 z4 = {0.0f, 0.0f, 0.0f, 0.0f};
                acc[mi][ni] = z4;
            }

        #pragma unroll 1
        for (int win = 0; win < 4; ++win) {
            // stage next window (next chunk wraps to window 0) into other buf
            if (!(c == NCH - 1 && win == 3)) STAGE(buf ^ 1, (win + 1) & 3);

            #pragma unroll 1
            for (int k8 = 0; k8 < 8; ++k8) {
                const int kt = win * 8 + k8;
                const unsigned short* q = pBc + (size_t)kt * KT_B;
                const bf16x8 b0 = *(const bf16x8*)(q);
                const bf16x8 b1 = *(const bf16x8*)(q + 512);
                const bf16x8 b2 = *(const bf16x8*)(q + 1024);
                const bf16x8 b3 = *(const bf16x8*)(q + 1536);
                const bf16x8 a0 = *(const bf16x8*)&LA[buf][k8][wh * 4 + 0][lane][0];
                const bf16x8 a1 = *(const bf16x8*)&LA[buf][k8][wh * 4 + 1][lane][0];
                const bf16x8 a2 = *(const bf16x8*)&LA[buf][k8][wh * 4 + 2][lane][0];
                const bf16x8 a3 = *(const bf16x8*)&LA[buf][k8][wh * 4 + 3][lane][0];
                __builtin_amdgcn_s_setprio(1);
                acc[0][0] = MM(a0, b0, acc[0][0]);
                acc[0][1] = MM(a0, b1, acc[0][1]);
                acc[0][2] = MM(a0, b2, acc[0][2]);
                acc[0][3] = MM(a0, b3, acc[0][3]);
                acc[1][0] = MM(a1, b0, acc[1][0]);
                acc[1][1] = MM(a1, b1, acc[1][1]);
                acc[1][2] = MM(a1, b2, acc[1][2]);
                acc[1][3] = MM(a1, b3, acc[1][3]);
                acc[2][0] = MM(a2, b0, acc[2][0]);
                acc[2][1] = MM(a2, b1, acc[2][1]);
                acc[2][2] = MM(a2, b2, acc[2][2]);
                acc[2][3] = MM(a2, b3, acc[2][3]);
                acc[3][0] = MM(a3, b0, acc[3][0]);
                acc[3][1] = MM(a3, b1, acc[3][1]);
                acc[3][2] = MM(a3, b2, acc[3][2]);
                acc[3][3] = MM(a3, b3, acc[3][3]);
                __builtin_amdgcn_s_setprio(0);
            }
            // window end: our 4 stage-GLLs are the only outstanding vmem
            asm volatile("s_waitcnt vmcnt(0)" ::: "memory");
            __syncthreads();
            buf ^= 1;
        }

        // merge chunk into LDS-held pos/neg maxes
        #pragma unroll
        for (int mi = 0; mi < 4; ++mi) {
            #pragma unroll
            for (int r = 0; r < 4; ++r) {
                const int row = mi * 16 + lk * 4 + r;          // 0..63 in half
                const unsigned yv = (unsigned)y[rowbase + wh * 64 + row];
                float pm = -INFINITY, nm = -INFINITY;
                #pragma unroll
                for (int ni = 0; ni < 4; ++ni) {
                    const unsigned col =
                        (unsigned)(ch * COLHALF + c * 512 + wc * 64 + ni * 16 + lm);
                    const unsigned lbl = __umulhi(col, 0xCCCCCCCDu) >> 2;  // /5
                    const float v = acc[mi][ni][r];
                    const bool same = (lbl == yv);
                    pm = same ? fmaxf(pm, v) : pm;
                    nm = (!same && col < NPROTO) ? fmaxf(nm, v) : nm;
                }
                #pragma unroll
                for (int off = 1; off < 16; off <<= 1) {
                    pm = fmaxf(pm, __shfl_xor(pm, off));
                    nm = fmaxf(nm, __shfl_xor(nm, off));
                }
                if (lm == 0) {   // lanes 0,16,32,48 -> 4 distinct rows
                    redP[w][row] = fmaxf(redP[w][row], pm);
                    redN[w][row] = fmaxf(redN[w][row], nm);
                }
            }
        }
    }

    __syncthreads();
    // merge the 8 col-slot waves of each row-half; write per-half buffers
    if (t < 128) {
        const int h = t >> 6, rr = t & 63;
        float p = redP[h * 8][rr], n = redN[h * 8][rr];
        #pragma unroll
        for (int i = 1; i < 8; ++i) {
            p = fmaxf(p, redP[h * 8 + i][rr]);
            n = fmaxf(n, redN[h * 8 + i][rr]);
        }
        outP[(size_t)ch * BATCH + rowbase + t] = p;
        outN[(size_t)ch * BATCH + rowbase + t] = n;
    }
#undef STAGE
}

// ---------- combine the two col-halves ----------
__global__ __launch_bounds__(256) void k_finish(
        const float* __restrict__ outP, const float* __restrict__ outN,
        float* __restrict__ out) {
    const int i = blockIdx.x * 256 + threadIdx.x;
    if (i < BATCH) {
        out[i] = fmaxf(outP[i], outP[BATCH + i]);
        out[BATCH + i] = fmaxf(outN[i], outN[BATCH + i]);
    }
}

extern "C" void kernel_launch(void* const* d_in, const int* in_sizes, int n_in,
                              void* d_out, int out_size, void* d_ws, size_t ws_size,
                              hipStream_t stream) {
    const float* z = (const float*)d_in[0];
    const int*   y = (const int*)d_in[1];
    const float* P = (const float*)d_in[2];

    // ws: abf 33.6MB | pbf 10.5MB | outP 128KB | outN 128KB
    unsigned short* abf = (unsigned short*)d_ws;
    unsigned short* pbf = abf + (size_t)NKT * KT_A;
    float* outP = (float*)(pbf + (size_t)NKT * KT_B);
    float* outN = outP + 2 * BATCH;
    float* out = (float*)d_out;

    k_prep<<<BATCH + NPROTO_PAD, 256, 0, stream>>>(z, P, abf, pbf);
    k_gemm<<<256, 1024, 0, stream>>>(abf, pbf, y, outP, outN);
    k_finish<<<(BATCH + 255) / 256, 256, 0, stream>>>(outP, outN, out);
}

// Round 15
// 172.690 us; speedup vs baseline: 1.2872x; 1.2872x over previous
//
#include <hip/hip_runtime.h>
#include <hip/hip_bf16.h>
#include <stdint.h>

#define BATCH 16384
#define D 1024
#define NCLS 1000
#define NPROTO 5000
#define NPROTO_PAD 5120
#define NGRP 320              // proto col-groups of 16
#define BM 64                 // rows per block (one block per CU)
#define NCH 5                 // N chunks of 1024 cols (16 waves x 64)
#define NKT 32                // K tiles of 32
#define KSTRIDE (NGRP * 64 * 8)   // pbf elems per kt

typedef float f32x4 __attribute__((ext_vector_type(4)));
typedef __bf16 bf16x8 __attribute__((ext_vector_type(8)));

__device__ __forceinline__ unsigned short f2bf(float x) {
    unsigned u = __float_as_uint(x);
    u += 0x7FFFu + ((u >> 16) & 1u);   // RNE
    return (unsigned short)(u >> 16);
}

// ---------- normalize rows of P to bf16, MFMA-fragment-packed ----------
// pbf[kt][grp][lane][8]: col = grp*16 + (lane&15), k = kt*32 + (lane>>4)*8 + e
// -> a wave's B-fragment load is one contiguous 1KB line
__global__ __launch_bounds__(256) void k_prep(
        const float* __restrict__ P, unsigned short* __restrict__ pbf) {
    const int r = blockIdx.x;             // proto row 0..5119
    const int t = threadIdx.x;
    const int e0 = 4 * t;
    const int kt = e0 >> 5;
    const int lk = (e0 >> 3) & 3;
    const int e = e0 & 7;
    unsigned short* dst =
        pbf + (((size_t)kt * NGRP + (r >> 4)) * 64 + (r & 15) + 16 * lk) * 8 + e;
    if (r >= NPROTO) {                    // padded proto row -> zeros
        *(ushort4*)dst = make_ushort4(0, 0, 0, 0);
        return;
    }
    const float* src = P + (size_t)r * D;
    float4 v = ((const float4*)src)[t];
    float ss = v.x * v.x + v.y * v.y + v.z * v.z + v.w * v.w;
    #pragma unroll
    for (int o = 32; o >= 1; o >>= 1) ss += __shfl_xor(ss, o);
    __shared__ float red[4];
    const int wave = t >> 6;
    if ((t & 63) == 0) red[wave] = ss;
    __syncthreads();
    const float s = red[0] + red[1] + red[2] + red[3];
    const float inv = 1.0f / fmaxf(sqrtf(s), 1e-12f);
    ushort4 o4;
    o4.x = f2bf(v.x * inv); o4.y = f2bf(v.y * inv);
    o4.z = f2bf(v.z * inv); o4.w = f2bf(v.w * inv);
    *(ushort4*)dst = o4;
}

#define MM(A, B, C) __builtin_amdgcn_mfma_f32_16x16x32_bf16(A, B, C, 0, 0, 0)

// ---------- persistent-tile GEMM: A normalized+resident in LDS, B streamed --
// 256 blocks x 1024 threads (16 waves = 4/SIMD). Wave tile 64x64 (acc[4][4]),
// single-buffered B (R11 structure — measured best). A-normalization fused:
// each block reads its 64 f32 z-rows once, normalizes, packs into LDS.
__global__ __launch_bounds__(1024, 4) void k_gemm(
        const float* __restrict__ z,
        const unsigned short* __restrict__ pbf,
        const int* __restrict__ y,
        float* __restrict__ out) {
    // A fragment-packed: LA[kt][row-group 0..3][lane][8]
    __shared__ __align__(16) unsigned short LA[NKT][4][64][8];   // 128 KiB
    __shared__ float redP[16][64];                               // 4 KiB
    __shared__ float redN[16][64];                               // 4 KiB

    const int t = threadIdx.x;
    const int w = t >> 6;                // wave 0..15 = N-slice
    const int lane = t & 63;
    const int lm = lane & 15, lk = lane >> 4;
    const int rowbase = blockIdx.x * BM;

    redP[w][lane] = -INFINITY;
    redN[w][lane] = -INFINITY;

    // ---- fused A-prep: row r = t>>4 (0..63), segment s = t&15 (64 f32) ----
    {
        const int r = t >> 4;
        const int s = t & 15;
        const float* zr = z + (size_t)(rowbase + r) * D + s * 64;
        float4 v[16];
        float ss = 0.0f;
        #pragma unroll
        for (int i = 0; i < 16; ++i) {
            v[i] = ((const float4*)zr)[i];
            ss += v[i].x * v[i].x + v[i].y * v[i].y +
                  v[i].z * v[i].z + v[i].w * v[i].w;
        }
        // reduce over the 16 threads of this row (same wave, contiguous)
        #pragma unroll
        for (int o = 1; o < 16; o <<= 1) ss += __shfl_xor(ss, o);
        const float inv = 1.0f / fmaxf(sqrtf(ss), 1e-12f);
        // pack: elems k0 = s*64 + j*8 -> LA[kt][r>>4][(r&15)+16*lk][8]
        #pragma unroll
        for (int j = 0; j < 8; ++j) {
            const int k0 = s * 64 + j * 8;
            const int kt = k0 >> 5;
            const int lkj = (k0 >> 3) & 3;
            const float4 va = v[2 * j], vb = v[2 * j + 1];
            ushort4 lo, hi;
            lo.x = f2bf(va.x * inv); lo.y = f2bf(va.y * inv);
            lo.z = f2bf(va.z * inv); lo.w = f2bf(va.w * inv);
            hi.x = f2bf(vb.x * inv); hi.y = f2bf(vb.y * inv);
            hi.z = f2bf(vb.z * inv); hi.w = f2bf(vb.w * inv);
            ushort4* d = (ushort4*)&LA[kt][r >> 4][(r & 15) + 16 * lkj][0];
            d[0] = lo; d[1] = hi;
        }
    }
    __syncthreads();

    // ---- N-chunk sweep: 5 chunks x 1024 cols; wave w owns cols w*64..+64 --
    #pragma unroll 1
    for (int c = 0; c < NCH; ++c) {
        const int grp0 = c * 64 + w * 4;
        const unsigned short* pB = pbf + ((size_t)grp0 * 64 + lane) * 8;

        f32x4 acc[4][4];
        #pragma unroll
        for (int mi = 0; mi < 4; ++mi)
            #pragma unroll
            for (int ni = 0; ni < 4; ++ni) {
                f32x4 z4 = {0.0f, 0.0f, 0.0f, 0.0f};
                acc[mi][ni] = z4;
            }

        #pragma unroll 1
        for (int kt = 0; kt < NKT; ++kt) {
            // B loads first (global), then LDS a-frags: both in flight;
            // 16 waves/CU cover the residual latency.
            const unsigned short* q = pB + (size_t)kt * KSTRIDE;
            const bf16x8 b0 = *(const bf16x8*)(q);
            const bf16x8 b1 = *(const bf16x8*)(q + 512);
            const bf16x8 b2 = *(const bf16x8*)(q + 1024);
            const bf16x8 b3 = *(const bf16x8*)(q + 1536);
            const bf16x8 a0 = *(const bf16x8*)&LA[kt][0][lane][0];
            const bf16x8 a1 = *(const bf16x8*)&LA[kt][1][lane][0];
            const bf16x8 a2 = *(const bf16x8*)&LA[kt][2][lane][0];
            const bf16x8 a3 = *(const bf16x8*)&LA[kt][3][lane][0];
            acc[0][0] = MM(a0, b0, acc[0][0]);
            acc[0][1] = MM(a0, b1, acc[0][1]);
            acc[0][2] = MM(a0, b2, acc[0][2]);
            acc[0][3] = MM(a0, b3, acc[0][3]);
            acc[1][0] = MM(a1, b0, acc[1][0]);
            acc[1][1] = MM(a1, b1, acc[1][1]);
            acc[1][2] = MM(a1, b2, acc[1][2]);
            acc[1][3] = MM(a1, b3, acc[1][3]);
            acc[2][0] = MM(a2, b0, acc[2][0]);
            acc[2][1] = MM(a2, b1, acc[2][1]);
            acc[2][2] = MM(a2, b2, acc[2][2]);
            acc[2][3] = MM(a2, b3, acc[2][3]);
            acc[3][0] = MM(a3, b0, acc[3][0]);
            acc[3][1] = MM(a3, b1, acc[3][1]);
            acc[3][2] = MM(a3, b2, acc[3][2]);
            acc[3][3] = MM(a3, b3, acc[3][3]);
        }

        // merge chunk into LDS-held pos/neg maxes (scalar transients only)
        #pragma unroll
        for (int mi = 0; mi < 4; ++mi) {
            #pragma unroll
            for (int r = 0; r < 4; ++r) {
                const int row = mi * 16 + lk * 4 + r;
                const unsigned yv = (unsigned)y[rowbase + row];
                float pm = -INFINITY, nm = -INFINITY;
                #pragma unroll
                for (int ni = 0; ni < 4; ++ni) {
                    const unsigned col = (unsigned)(c * 1024 + w * 64 + ni * 16 + lm);
                    const unsigned lbl = __umulhi(col, 0xCCCCCCCDu) >> 2; // col/5
                    const float v = acc[mi][ni][r];
                    const bool same = (lbl == yv);
                    pm = same ? fmaxf(pm, v) : pm;
                    nm = (!same && col < NPROTO) ? fmaxf(nm, v) : nm;
                }
                #pragma unroll
                for (int off = 1; off < 16; off <<= 1) {
                    pm = fmaxf(pm, __shfl_xor(pm, off));
                    nm = fmaxf(nm, __shfl_xor(nm, off));
                }
                if (lm == 0) {   // lanes 0,16,32,48 -> distinct rows, same wave
                    redP[w][row] = fmaxf(redP[w][row], pm);
                    redN[w][row] = fmaxf(redN[w][row], nm);
                }
            }
        }
    }

    __syncthreads();
    // final cross-wave merge + direct output write (no atomics)
    if (t < 64) {
        float p = redP[0][t], n = redN[0][t];
        #pragma unroll
        for (int ww = 1; ww < 16; ++ww) {
            p = fmaxf(p, redP[ww][t]);
            n = fmaxf(n, redN[ww][t]);
        }
        out[rowbase + t] = p;
        out[BATCH + rowbase + t] = n;
    }
}

extern "C" void kernel_launch(void* const* d_in, const int* in_sizes, int n_in,
                              void* d_out, int out_size, void* d_ws, size_t ws_size,
                              hipStream_t stream) {
    const float* z = (const float*)d_in[0];
    const int*   y = (const int*)d_in[1];
    const float* P = (const float*)d_in[2];

    // ws: pbf 10.5MB
    unsigned short* pbf = (unsigned short*)d_ws;
    float* out = (float*)d_out;

    k_prep<<<NPROTO_PAD, 256, 0, stream>>>(P, pbf);
    k_gemm<<<BATCH / BM, 1024, 0, stream>>>(z, pbf, y, out);
}